// Round 10
// baseline (158.082 us; speedup 1.0000x reference)
//
#include <hip/hip_runtime.h>
#include <hip/hip_bf16.h>
#include <cstdint>

#define DEV __device__ __forceinline__

typedef float f32x4 __attribute__((ext_vector_type(4)));
typedef short bf16x8 __attribute__((ext_vector_type(8)));
typedef unsigned short u16;
typedef unsigned int u32;

constexpr int Bb = 2, Nn = 2048, Cc = 1024, Hh = 16, Dd = 64;
// 64^-0.5 * log2(e): folded into w_qkv's Q-rows at cvt; softmax runs in exp2 domain.
constexpr float QSCALE = 0.18033688011112042f;

// fp32 -> bf16 round-to-nearest-even
DEV u16 f2b(float f) {
  unsigned u = __float_as_uint(f);
  u += 0x7FFFu + ((u >> 16) & 1u);
  return (u16)(u >> 16);
}

DEV void gload_lds16(const u16* g, u16* l) {
  __builtin_amdgcn_global_load_lds(
      (const __attribute__((address_space(1))) void*)g,
      (__attribute__((address_space(3))) void*)l, 16, 0, 0);
}

// XOR swizzle for LDS tiles with 128B rows (64 bf16/row) — attn K/V tiles.
DEV int swz(int row, int byteInRow) {
  return row * 128 + (byteInRow ^ ((row & 7) << 4));
}
// 64B-row variant (GEMM BK=32 tiles)
DEV int swzp(int row, int byteInRow) {
  return row * 64 + (byteInRow ^ ((((row >> 2) + row) & 3) << 4));
}

DEV u32 cvtpk(float lo, float hi) {
  u32 r;
  asm("v_cvt_pk_bf16_f32 %0, %1, %2" : "=v"(r) : "v"(lo), "v"(hi));
  return r;
}
DEV void pl32swap(u32& a, u32& b) {
  asm("v_permlane32_swap_b32 %0, %1" : "+v"(a), "+v"(b));
}
DEV void pl16swap(u32& a, u32& b) {
  asm("v_permlane16_swap_b32 %0, %1" : "+v"(a), "+v"(b));
}

#if __has_builtin(__builtin_amdgcn_exp2f)
DEV float fast_exp2(float x) { return __builtin_amdgcn_exp2f(x); }
#else
DEV float fast_exp2(float x) { return exp2f(x); }
#endif

// ---------------- fused fp32 -> bf16 convert; scales w_qkv's Q-rows by QSCALE ----------------
__global__ void cvt_all(const float* __restrict__ x, u16* __restrict__ xb,
                        const float* __restrict__ wq, u16* __restrict__ wqb,
                        const float* __restrict__ wp, u16* __restrict__ wpb) {
  constexpr int n1 = 4096 * 1024 / 4, n2 = 3072 * 1024 / 4, n3 = 1024 * 1024 / 4;
  constexpr int nQ = 1024 * 1024 / 4;  // first 1024 rows of w_qkv = Q
  int idx = blockIdx.x * blockDim.x + threadIdx.x;
  int stride = gridDim.x * blockDim.x;
  for (int i = idx; i < n1 + n2 + n3; i += stride) {
    const float* in; u16* out; int j;
    float sc = 1.f;
    if (i < n1) { in = x; out = xb; j = i; }
    else if (i < n1 + n2) { in = wq; out = wqb; j = i - n1; if (j < nQ) sc = QSCALE; }
    else { in = wp; out = wpb; j = i - n1 - n2; }
    float4 v = ((const float4*)in)[j];
    ushort4 o;
    o.x = f2b(v.x * sc); o.y = f2b(v.y * sc); o.z = f2b(v.z * sc); o.w = f2b(v.w * sc);
    ((ushort4*)out)[j] = o;
  }
}

// ---------------- QKV GEMM: 128x128, BK=32, 3 blocks/CU, 1-barrier dbuf (unchanged) ----------------
__global__ __launch_bounds__(256) void gemm_qkv(
    const u16* __restrict__ A, const u16* __restrict__ W, u16* __restrict__ qkv_out) {
  constexpr int K = 1024, NT = K / 32;
  __shared__ __align__(16) u16 As[2][128 * 32];
  __shared__ __align__(16) u16 Bs[2][128 * 32];
  const int t = threadIdx.x, lane = t & 63;
  const int wm = t >> 7, wn = (t >> 6) & 1;
  const int bid = blockIdx.x;
  const int wg = (bid & 7) * 96 + (bid >> 3);
  const int bx = wg % 24, by = wg / 24;
  const int m0 = by * 128, n0 = bx * 128;
  const int fr = lane & 15, g = lane >> 4;

  const int srow = t >> 2;
  const int scp = (t & 3) ^ (((t >> 2) + (t >> 4)) & 3);
  const u16* gA = A + (size_t)(m0 + srow) * K + scp * 8;
  const u16* gW = W + (size_t)(n0 + srow) * K + scp * 8;

  f32x4 acc[4][4] = {};

#define STAGEQ(tile, buf)                                              \
  {                                                                    \
    const int k0_ = (tile) * 32;                                       \
    gload_lds16(gA + k0_, &As[buf][t * 8]);                            \
    gload_lds16(gA + k0_ + (size_t)64 * K, &As[buf][t * 8 + 2048]);    \
    gload_lds16(gW + k0_, &Bs[buf][t * 8]);                            \
    gload_lds16(gW + k0_ + (size_t)64 * K, &Bs[buf][t * 8 + 2048]);    \
  }

  STAGEQ(0, 0);
  __syncthreads();

  for (int tt = 0; tt < NT; ++tt) {
    const int cur = tt & 1;
    if (tt + 1 < NT) STAGEQ(tt + 1, cur ^ 1);
    const char* Ac = (const char*)As[cur];
    const char* Bc = (const char*)Bs[cur];
    bf16x8 af[4], bfr[4];
#pragma unroll
    for (int i = 0; i < 4; ++i)
      af[i] = *(const bf16x8*)(Ac + swzp(wm * 64 + i * 16 + fr, g * 16));
#pragma unroll
    for (int j = 0; j < 4; ++j)
      bfr[j] = *(const bf16x8*)(Bc + swzp(wn * 64 + j * 16 + fr, g * 16));
    __builtin_amdgcn_s_setprio(1);
#pragma unroll
    for (int i = 0; i < 4; ++i)
#pragma unroll
      for (int j = 0; j < 4; ++j)
        acc[i][j] = __builtin_amdgcn_mfma_f32_16x16x32_bf16(af[i], bfr[j], acc[i][j], 0, 0, 0);
    __builtin_amdgcn_s_setprio(0);
    __syncthreads();
  }

  const int rg = g * 4;
#pragma unroll
  for (int mi = 0; mi < 4; ++mi) {
#pragma unroll
    for (int ni = 0; ni < 4; ++ni) {
      const int col = n0 + wn * 64 + ni * 16 + fr;
      const int s = col >> 10, h = (col >> 6) & 15, d = col & 63;
      const int row0 = m0 + wm * 64 + mi * 16 + rg;
      const int b = row0 >> 11, nb = row0 & 2047;
      if (s == 2) {
        ushort4 o4;
        o4.x = f2b(acc[mi][ni][0]); o4.y = f2b(acc[mi][ni][1]);
        o4.z = f2b(acc[mi][ni][2]); o4.w = f2b(acc[mi][ni][3]);
        const size_t off = (size_t)2 * Bb * Hh * Nn * Dd +
                           (((size_t)b * Hh + h) * Dd + d) * Nn + nb;
        *(ushort4*)&qkv_out[off] = o4;
      } else {
#pragma unroll
        for (int r = 0; r < 4; ++r) {
          const size_t off = ((((size_t)s * Bb + b) * Hh + h) * Nn + (nb + r)) * Dd + d;
          qkv_out[off] = f2b(acc[mi][ni][r]);
        }
      }
    }
  }
#undef STAGEQ
}

// ---------------- proj GEMM: 128x128 tile, BK=32, dbuf stage-ahead (round-7 exact) ----------------
__global__ __launch_bounds__(256) void gemm_proj(
    const u16* __restrict__ A, const u16* __restrict__ W,
    float* __restrict__ fout, const float* __restrict__ bias) {
  constexpr int K = 1024, Nmat = 1024, NT = K / 32;
  __shared__ __align__(16) u16 As[2][128 * 32];
  __shared__ __align__(16) u16 Bs[2][128 * 32];
  const int t = threadIdx.x, lane = t & 63;
  const int wm = t >> 7, wn = (t >> 6) & 1;
  const int bid = blockIdx.x;
  const int wg = (bid & 7) * 32 + (bid >> 3);
  const int bx = wg & 7, by = wg >> 3;
  const int m0 = by * 128, n0 = bx * 128;
  const int fr = lane & 15, g = lane >> 4;

  const int srow = t >> 2;
  const int scp = (t & 3) ^ (((t >> 2) + (t >> 4)) & 3);
  const u16* gA = A + (size_t)(m0 + srow) * K + scp * 8;
  const u16* gW = W + (size_t)(n0 + srow) * K + scp * 8;

  f32x4 acc[4][4] = {};

#define STAGEP(tile, buf)                                              \
  {                                                                    \
    const int k0_ = (tile) * 32;                                       \
    gload_lds16(gA + k0_, &As[buf][t * 8]);                            \
    gload_lds16(gA + k0_ + (size_t)64 * K, &As[buf][t * 8 + 2048]);    \
    gload_lds16(gW + k0_, &Bs[buf][t * 8]);                            \
    gload_lds16(gW + k0_ + (size_t)64 * K, &Bs[buf][t * 8 + 2048]);    \
  }

  STAGEP(0, 0);
  __syncthreads();

  for (int tt = 0; tt < NT; ++tt) {
    const int cur = tt & 1;
    if (tt + 1 < NT) STAGEP(tt + 1, cur ^ 1);
    const char* Ac = (const char*)As[cur];
    const char* Bc = (const char*)Bs[cur];
    bf16x8 af[4], bfr[4];
#pragma unroll
    for (int i = 0; i < 4; ++i)
      af[i] = *(const bf16x8*)(Ac + swzp(wm * 64 + i * 16 + fr, g * 16));
#pragma unroll
    for (int j = 0; j < 4; ++j)
      bfr[j] = *(const bf16x8*)(Bc + swzp(wn * 64 + j * 16 + fr, g * 16));
    __builtin_amdgcn_s_setprio(1);
#pragma unroll
    for (int i = 0; i < 4; ++i)
#pragma unroll
      for (int j = 0; j < 4; ++j)
        acc[i][j] = __builtin_amdgcn_mfma_f32_16x16x32_bf16(af[i], bfr[j], acc[i][j], 0, 0, 0);
    __builtin_amdgcn_s_setprio(0);
    __syncthreads();
  }

  const int rg = g * 4;
#pragma unroll
  for (int i = 0; i < 4; ++i)
#pragma unroll
    for (int j = 0; j < 4; ++j) {
      const int col = n0 + wn * 64 + j * 16 + fr;
#pragma unroll
      for (int r = 0; r < 4; ++r) {
        const int row = m0 + wm * 64 + i * 16 + rg + r;
        fout[(size_t)row * Nmat + col] = acc[i][j][r] + bias[col];
      }
    }
#undef STAGEP
}

// ---------------- flash attention v6: Q-split x2, 32 waves/CU, round-7 staging ----------------
// 1 block = 64 q-rows x full 2048 kv of one (b,h), 512 threads; grid 1024
// (4 blocks/CU -> 32 waves/CU). Wave w: qg=w>>1 (16 q-rows, reg B-frags),
// kh=w&1 (32 kv of the 64-kv tile). Staging = round-7 LOADT/STORET (register
// loads + swizzled ds_write; PROVEN). P = exp2(S^T) direct (no max tracking),
// lse via ones-MFMA; kh-halves combined through LDS; single output, no
// cross-block combine. Cost vs round 7: K/V staged 2x per head (L2-resident).
__global__ __launch_bounds__(512, 8) void attn_fwd(
    const u16* __restrict__ Qg, const u16* __restrict__ Kg,
    const u16* __restrict__ Vtg, u16* __restrict__ Og) {
  __shared__ __align__(16) char smem[34816];  // [0,32768): K/V dbuf; epilogue aliases
  const int t = threadIdx.x, lane = t & 63, w = t >> 6;
  const int qg = w >> 1, kh = w & 1;
  // XCD swizzle: the 32 q-blocks of one head land on one XCD's L2 (4 heads/XCD).
  const int wg = ((blockIdx.x & 7) << 7) | (blockIdx.x >> 3);
  const int bh = wg >> 5;
  const int q0 = (wg & 31) * 64;
  const size_t base = (size_t)bh * Nn * Dd;
  const u16* Qb = Qg + base;
  const u16* Kb = Kg + base;
  const u16* Vb = Vtg + base;  // [D=64][N=2048]
  const int fr = lane & 15, g = lane >> 4;

  bf16x8 onesv;
  {
    union { u32 u[4]; bf16x8 v; } o_;
#pragma unroll
    for (int i = 0; i < 4; ++i) o_.u[i] = 0x3F803F80u;
    onesv = o_.v;
  }

  // Q as MFMA-B fragments: 16 q-rows per wave
  bf16x8 qf[2];
#pragma unroll
  for (int dc = 0; dc < 2; ++dc)
    qf[dc] = *(const bf16x8*)&Qb[(size_t)(q0 + qg * 16 + fr) * 64 + dc * 32 + g * 8];

  f32x4 ot[4] = {};            // [dt]: O^T partial, rows d, col q = fr
  float lse = 0.f;

  // block-cooperative staging (round-7 exact): 512 threads, 1 uint4 K + 1 V
  const int srow = t >> 3, scb = t & 7;   // srow in [0,64)
  const u16* kp = Kb + srow * 64 + scb * 8;
  const u16* vp = Vb + (size_t)srow * Nn + scb * 8;
  uint4 kreg, vreg;

#define LOADT(tile)                                        \
  {                                                        \
    kreg = *(const uint4*)(kp + (size_t)(tile) * 4096);    \
    vreg = *(const uint4*)(vp + (size_t)(tile) * 64);      \
  }
#define STORET(buf)                                        \
  {                                                        \
    char* kb_ = smem + (buf) * 16384;                      \
    *(uint4*)(kb_ + swz(srow, scb * 16)) = kreg;           \
    *(uint4*)(kb_ + 8192 + swz(srow, scb * 16)) = vreg;    \
  }

  LOADT(0);
  STORET(0);
  __syncthreads();

  for (int it = 0; it < 32; ++it) {
    const int cur = it & 1;
    const char* Kst = smem + cur * 16384;
    const char* Vst = Kst + 8192;
    if (it < 31) LOADT(it + 1);  // issue-early; lands under compute (T14)

    // ---- S^T = K_half · Q^T : rows kv (kh*32 + kvt*16 + 4g + r), col q = fr ----
    bf16x8 kf[2][2];
#pragma unroll
    for (int kvt = 0; kvt < 2; ++kvt)
#pragma unroll
      for (int dc = 0; dc < 2; ++dc)
        kf[kvt][dc] = *(const bf16x8*)(Kst + swz(kh * 32 + kvt * 16 + fr, dc * 64 + g * 16));
    f32x4 st[2] = {};
    __builtin_amdgcn_s_setprio(1);
#pragma unroll
    for (int dc = 0; dc < 2; ++dc)
#pragma unroll
      for (int kvt = 0; kvt < 2; ++kvt)
        st[kvt] = __builtin_amdgcn_mfma_f32_16x16x32_bf16(kf[kvt][dc], qf[dc], st[kvt], 0, 0, 0);
    __builtin_amdgcn_s_setprio(0);

    // ---- P = exp2(S^T); assemble P^T B-frag in registers ----
#pragma unroll
    for (int kvt = 0; kvt < 2; ++kvt)
#pragma unroll
      for (int r = 0; r < 4; ++r)
        st[kvt][r] = fast_exp2(st[kvt][r]);

    u32 a0 = cvtpk(st[0][0], st[0][1]);
    u32 a1 = cvtpk(st[0][2], st[0][3]);
    u32 b0 = cvtpk(st[1][0], st[1][1]);
    u32 b1 = cvtpk(st[1][2], st[1][3]);
    pl32swap(a0, b0); pl16swap(a0, b0);
    pl32swap(a1, b1); pl16swap(a1, b1);

    // ---- lse via ones-MFMA; O^T += V_half^T · P^T ----
    bf16x8 vf[4];
#pragma unroll
    for (int dt = 0; dt < 4; ++dt)
      vf[dt] = *(const bf16x8*)(Vst + swz(dt * 16 + fr, kh * 64 + g * 16));
    __builtin_amdgcn_s_setprio(1);
    {
      union { u32 u[4]; bf16x8 v; } pu;
      pu.u[0] = a0; pu.u[1] = a1; pu.u[2] = b0; pu.u[3] = b1;
      f32x4 z = {0.f, 0.f, 0.f, 0.f};
      f32x4 rsv = __builtin_amdgcn_mfma_f32_16x16x32_bf16(onesv, pu.v, z, 0, 0, 0);
      lse += rsv[0];
#pragma unroll
      for (int dt = 0; dt < 4; ++dt)
        ot[dt] = __builtin_amdgcn_mfma_f32_16x16x32_bf16(vf[dt], pu.v, ot[dt], 0, 0, 0);
    }
    __builtin_amdgcn_s_setprio(0);

    if (it < 31) {
      STORET(cur ^ 1);   // writes buf cur^1; all reads this iter hit buf cur
      __syncthreads();   // single barrier per iter
    }
  }

  // ---- combine kh-halves through LDS (aliases dead K/V buffers) ----
  __syncthreads();
  float* Ob = (float*)(smem + qg * 4224);            // [16 q][stride 66] f32
  float* Lb = (float*)(smem + 16896 + qg * 64);      // [16 q] f32
  if (kh) {
#pragma unroll
    for (int dt = 0; dt < 4; ++dt)
#pragma unroll
      for (int r = 0; r < 4; ++r)
        Ob[fr * 66 + dt * 16 + 4 * g + r] = ot[dt][r];
    if (g == 0) Lb[fr] = lse;
  }
  __syncthreads();
  if (!kh) {
    const int b = bh >> 4, h = bh & 15;
    const float inv = 1.f / (lse + Lb[fr]);
    const int tok = q0 + qg * 16 + fr;
    const size_t rowbase = ((size_t)b * Nn + tok) * Cc + h * 64;
#pragma unroll
    for (int dt = 0; dt < 4; ++dt) {
      ushort4 o4;
      o4.x = f2b((ot[dt][0] + Ob[fr * 66 + dt * 16 + 4 * g + 0]) * inv);
      o4.y = f2b((ot[dt][1] + Ob[fr * 66 + dt * 16 + 4 * g + 1]) * inv);
      o4.z = f2b((ot[dt][2] + Ob[fr * 66 + dt * 16 + 4 * g + 2]) * inv);
      o4.w = f2b((ot[dt][3] + Ob[fr * 66 + dt * 16 + 4 * g + 3]) * inv);
      *(ushort4*)&Og[rowbase + dt * 16 + g * 4] = o4;
    }
  }
#undef LOADT
#undef STORET
}

extern "C" void kernel_launch(void* const* d_in, const int* in_sizes, int n_in,
                              void* d_out, int out_size, void* d_ws, size_t ws_size,
                              hipStream_t stream) {
  const float* x      = (const float*)d_in[0];
  const float* w_qkv  = (const float*)d_in[1];
  const float* w_proj = (const float*)d_in[2];
  const float* b_proj = (const float*)d_in[3];
  float* out = (float*)d_out;

  // ws layout — 48 MB, round-7 exact:
  u16* xb     = (u16*)d_ws;                        // 4096*1024
  u16* wqkvb  = xb + (size_t)4096 * 1024;          // 3072*1024
  u16* wprojb = wqkvb + (size_t)3072 * 1024;       // 1024*1024
  u16* qkv    = wprojb + (size_t)1024 * 1024;      // 3*2*16*2048*64
  u16* ows    = qkv + (size_t)3 * Bb * Hh * Nn * Dd;  // 4096*1024
  u16* q  = qkv;
  u16* k  = qkv + (size_t)Bb * Hh * Nn * Dd;
  u16* vt = k + (size_t)Bb * Hh * Nn * Dd;         // [B][H][D][N]

  cvt_all<<<2048, 256, 0, stream>>>(x, xb, w_qkv, wqkvb, w_proj, wprojb);
  gemm_qkv<<<768, 256, 0, stream>>>(xb, wqkvb, qkv);
  attn_fwd<<<1024, 512, 0, stream>>>(q, k, vt, ows);
  gemm_proj<<<256, 256, 0, stream>>>(ows, wprojb, out, b_proj);
}

// Round 11
// 135.157 us; speedup vs baseline: 1.1696x; 1.1696x over previous
//
#include <hip/hip_runtime.h>
#include <hip/hip_bf16.h>
#include <cstdint>

#define DEV __device__ __forceinline__

typedef float f32x4 __attribute__((ext_vector_type(4)));
typedef short bf16x8 __attribute__((ext_vector_type(8)));
typedef unsigned short u16;
typedef unsigned int u32;

constexpr int Bb = 2, Nn = 2048, Cc = 1024, Hh = 16, Dd = 64;
// 64^-0.5 * log2(e): folded into w_qkv's Q-rows at cvt; softmax runs in exp2 domain.
constexpr float QSCALE = 0.18033688011112042f;

// fp32 -> bf16 round-to-nearest-even
DEV u16 f2b(float f) {
  unsigned u = __float_as_uint(f);
  u += 0x7FFFu + ((u >> 16) & 1u);
  return (u16)(u >> 16);
}

DEV void gload_lds16(const u16* g, u16* l) {
  __builtin_amdgcn_global_load_lds(
      (const __attribute__((address_space(1))) void*)g,
      (__attribute__((address_space(3))) void*)l, 16, 0, 0);
}

// 64B-row XOR swizzle (GEMM BK=32 LDS tiles)
DEV int swzp(int row, int byteInRow) {
  return row * 64 + (byteInRow ^ ((((row >> 2) + row) & 3) << 4));
}

DEV u32 cvtpk(float lo, float hi) {
  u32 r;
  asm("v_cvt_pk_bf16_f32 %0, %1, %2" : "=v"(r) : "v"(lo), "v"(hi));
  return r;
}
DEV void pl32swap(u32& a, u32& b) {
  asm("v_permlane32_swap_b32 %0, %1" : "+v"(a), "+v"(b));
}
DEV void pl16swap(u32& a, u32& b) {
  asm("v_permlane16_swap_b32 %0, %1" : "+v"(a), "+v"(b));
}

#if __has_builtin(__builtin_amdgcn_exp2f)
DEV float fast_exp2(float x) { return __builtin_amdgcn_exp2f(x); }
#else
DEV float fast_exp2(float x) { return exp2f(x); }
#endif

// ---------------- fused fp32 -> bf16 convert; scales w_qkv's Q-rows by QSCALE ----------------
__global__ void cvt_all(const float* __restrict__ x, u16* __restrict__ xb,
                        const float* __restrict__ wq, u16* __restrict__ wqb,
                        const float* __restrict__ wp, u16* __restrict__ wpb) {
  constexpr int n1 = 4096 * 1024 / 4, n2 = 3072 * 1024 / 4, n3 = 1024 * 1024 / 4;
  constexpr int nQ = 1024 * 1024 / 4;  // first 1024 rows of w_qkv = Q
  int idx = blockIdx.x * blockDim.x + threadIdx.x;
  int stride = gridDim.x * blockDim.x;
  for (int i = idx; i < n1 + n2 + n3; i += stride) {
    const float* in; u16* out; int j;
    float sc = 1.f;
    if (i < n1) { in = x; out = xb; j = i; }
    else if (i < n1 + n2) { in = wq; out = wqb; j = i - n1; if (j < nQ) sc = QSCALE; }
    else { in = wp; out = wpb; j = i - n1 - n2; }
    float4 v = ((const float4*)in)[j];
    ushort4 o;
    o.x = f2b(v.x * sc); o.y = f2b(v.y * sc); o.z = f2b(v.z * sc); o.w = f2b(v.w * sc);
    ((ushort4*)out)[j] = o;
  }
}

// ---------------- QKV GEMM: 128x128, BK=32, 3 blocks/CU, 1-barrier dbuf (unchanged) ----------------
__global__ __launch_bounds__(256) void gemm_qkv(
    const u16* __restrict__ A, const u16* __restrict__ W, u16* __restrict__ qkv_out) {
  constexpr int K = 1024, NT = K / 32;
  __shared__ __align__(16) u16 As[2][128 * 32];
  __shared__ __align__(16) u16 Bs[2][128 * 32];
  const int t = threadIdx.x, lane = t & 63;
  const int wm = t >> 7, wn = (t >> 6) & 1;
  const int bid = blockIdx.x;
  const int wg = (bid & 7) * 96 + (bid >> 3);
  const int bx = wg % 24, by = wg / 24;
  const int m0 = by * 128, n0 = bx * 128;
  const int fr = lane & 15, g = lane >> 4;

  const int srow = t >> 2;
  const int scp = (t & 3) ^ (((t >> 2) + (t >> 4)) & 3);
  const u16* gA = A + (size_t)(m0 + srow) * K + scp * 8;
  const u16* gW = W + (size_t)(n0 + srow) * K + scp * 8;

  f32x4 acc[4][4] = {};

#define STAGEQ(tile, buf)                                              \
  {                                                                    \
    const int k0_ = (tile) * 32;                                       \
    gload_lds16(gA + k0_, &As[buf][t * 8]);                            \
    gload_lds16(gA + k0_ + (size_t)64 * K, &As[buf][t * 8 + 2048]);    \
    gload_lds16(gW + k0_, &Bs[buf][t * 8]);                            \
    gload_lds16(gW + k0_ + (size_t)64 * K, &Bs[buf][t * 8 + 2048]);    \
  }

  STAGEQ(0, 0);
  __syncthreads();

  for (int tt = 0; tt < NT; ++tt) {
    const int cur = tt & 1;
    if (tt + 1 < NT) STAGEQ(tt + 1, cur ^ 1);
    const char* Ac = (const char*)As[cur];
    const char* Bc = (const char*)Bs[cur];
    bf16x8 af[4], bfr[4];
#pragma unroll
    for (int i = 0; i < 4; ++i)
      af[i] = *(const bf16x8*)(Ac + swzp(wm * 64 + i * 16 + fr, g * 16));
#pragma unroll
    for (int j = 0; j < 4; ++j)
      bfr[j] = *(const bf16x8*)(Bc + swzp(wn * 64 + j * 16 + fr, g * 16));
    __builtin_amdgcn_s_setprio(1);
#pragma unroll
    for (int i = 0; i < 4; ++i)
#pragma unroll
      for (int j = 0; j < 4; ++j)
        acc[i][j] = __builtin_amdgcn_mfma_f32_16x16x32_bf16(af[i], bfr[j], acc[i][j], 0, 0, 0);
    __builtin_amdgcn_s_setprio(0);
    __syncthreads();
  }

  const int rg = g * 4;
#pragma unroll
  for (int mi = 0; mi < 4; ++mi) {
#pragma unroll
    for (int ni = 0; ni < 4; ++ni) {
      const int col = n0 + wn * 64 + ni * 16 + fr;
      const int s = col >> 10, h = (col >> 6) & 15, d = col & 63;
      const int row0 = m0 + wm * 64 + mi * 16 + rg;
      const int b = row0 >> 11, nb = row0 & 2047;
      if (s == 2) {
        ushort4 o4;
        o4.x = f2b(acc[mi][ni][0]); o4.y = f2b(acc[mi][ni][1]);
        o4.z = f2b(acc[mi][ni][2]); o4.w = f2b(acc[mi][ni][3]);
        const size_t off = (size_t)2 * Bb * Hh * Nn * Dd +
                           (((size_t)b * Hh + h) * Dd + d) * Nn + nb;
        *(ushort4*)&qkv_out[off] = o4;
      } else {
#pragma unroll
        for (int r = 0; r < 4; ++r) {
          const size_t off = ((((size_t)s * Bb + b) * Hh + h) * Nn + (nb + r)) * Dd + d;
          qkv_out[off] = f2b(acc[mi][ni][r]);
        }
      }
    }
  }
#undef STAGEQ
}

// ---------------- proj GEMM: 128x128 tile, BK=32, dbuf stage-ahead (unchanged) ----------------
__global__ __launch_bounds__(256) void gemm_proj(
    const u16* __restrict__ A, const u16* __restrict__ W,
    float* __restrict__ fout, const float* __restrict__ bias) {
  constexpr int K = 1024, Nmat = 1024, NT = K / 32;
  __shared__ __align__(16) u16 As[2][128 * 32];
  __shared__ __align__(16) u16 Bs[2][128 * 32];
  const int t = threadIdx.x, lane = t & 63;
  const int wm = t >> 7, wn = (t >> 6) & 1;
  const int bid = blockIdx.x;
  const int wg = (bid & 7) * 32 + (bid >> 3);
  const int bx = wg & 7, by = wg >> 3;
  const int m0 = by * 128, n0 = bx * 128;
  const int fr = lane & 15, g = lane >> 4;

  const int srow = t >> 2;
  const int scp = (t & 3) ^ (((t >> 2) + (t >> 4)) & 3);
  const u16* gA = A + (size_t)(m0 + srow) * K + scp * 8;
  const u16* gW = W + (size_t)(n0 + srow) * K + scp * 8;

  f32x4 acc[4][4] = {};

#define STAGEP(tile, buf)                                              \
  {                                                                    \
    const int k0_ = (tile) * 32;                                       \
    gload_lds16(gA + k0_, &As[buf][t * 8]);                            \
    gload_lds16(gA + k0_ + (size_t)64 * K, &As[buf][t * 8 + 2048]);    \
    gload_lds16(gW + k0_, &Bs[buf][t * 8]);                            \
    gload_lds16(gW + k0_ + (size_t)64 * K, &Bs[buf][t * 8 + 2048]);    \
  }

  STAGEP(0, 0);
  __syncthreads();

  for (int tt = 0; tt < NT; ++tt) {
    const int cur = tt & 1;
    if (tt + 1 < NT) STAGEP(tt + 1, cur ^ 1);
    const char* Ac = (const char*)As[cur];
    const char* Bc = (const char*)Bs[cur];
    bf16x8 af[4], bfr[4];
#pragma unroll
    for (int i = 0; i < 4; ++i)
      af[i] = *(const bf16x8*)(Ac + swzp(wm * 64 + i * 16 + fr, g * 16));
#pragma unroll
    for (int j = 0; j < 4; ++j)
      bfr[j] = *(const bf16x8*)(Bc + swzp(wn * 64 + j * 16 + fr, g * 16));
    __builtin_amdgcn_s_setprio(1);
#pragma unroll
    for (int i = 0; i < 4; ++i)
#pragma unroll
      for (int j = 0; j < 4; ++j)
        acc[i][j] = __builtin_amdgcn_mfma_f32_16x16x32_bf16(af[i], bfr[j], acc[i][j], 0, 0, 0);
    __builtin_amdgcn_s_setprio(0);
    __syncthreads();
  }

  const int rg = g * 4;
#pragma unroll
  for (int i = 0; i < 4; ++i)
#pragma unroll
    for (int j = 0; j < 4; ++j) {
      const int col = n0 + wn * 64 + j * 16 + fr;
#pragma unroll
      for (int r = 0; r < 4; ++r) {
        const int row = m0 + wm * 64 + i * 16 + rg + r;
        fout[(size_t)row * Nmat + col] = acc[i][j][r] + bias[col];
      }
    }
#undef STAGEP
}

// ---------------- flash attention v7: zero-LDS, L2-direct fragments ----------------
// K/V per head = 512 KB; XCD swizzle puts 4 heads per XCD -> 2 MB, L2-resident
// (guide m169: don't LDS-stage what L2 fits). 1 block = 256 q-rows, 4 waves;
// each wave owns 64 q-rows x full 2048 kv. Grid 256 (1 wave/SIMD, pure ILP).
// Per 32-kv step: 8 frag loads (global->VGPR, L2), 16 QK MFMA, 32 exp2,
// pack/permlane (verified path), 16 PV + 4 lse MFMA. Register ping-pong
// prefetch hides L2 latency under compute. No LDS, no barriers.
__global__ __launch_bounds__(256, 1) void attn_fwd(
    const u16* __restrict__ Qg, const u16* __restrict__ Kg,
    const u16* __restrict__ Vtg, u16* __restrict__ Og) {
  const int t = threadIdx.x, lane = t & 63, w = t >> 6;
  // XCD swizzle: 256 blocks -> 32 contiguous per XCD -> 4 heads/XCD in L2.
  const int wg = ((blockIdx.x & 7) << 5) | (blockIdx.x >> 3);
  const int bh = wg >> 3;
  const int q0 = (wg & 7) * 256 + w * 64;
  const size_t base = (size_t)bh * Nn * Dd;
  const u16* Qb = Qg + base;
  const u16* Kb = Kg + base;
  const u16* Vb = Vtg + base;  // [D=64][N=2048]
  const int fr = lane & 15, g = lane >> 4;

  bf16x8 onesv;
  {
    union { u32 u[4]; bf16x8 v; } o_;
#pragma unroll
    for (int i = 0; i < 4; ++i) o_.u[i] = 0x3F803F80u;
    onesv = o_.v;
  }

  // Q as MFMA-B fragments: 64 q-rows in registers for the whole kernel
  bf16x8 qf[4][2];
#pragma unroll
  for (int qt = 0; qt < 4; ++qt)
#pragma unroll
    for (int dc = 0; dc < 2; ++dc)
      qf[qt][dc] = *(const bf16x8*)&Qb[(size_t)(q0 + qt * 16 + fr) * 64 + dc * 32 + g * 8];

  f32x4 ot[4][4] = {};             // [dt][qt]: O^T accum, row d, col q = fr
  float lse[4] = {0.f, 0.f, 0.f, 0.f};

  // K A-frag (16kv x 32d): lane(fr,g) -> K[kv0+kvt*16+fr][dc*32+g*8 ..+8]
#define LOADK(kv0, kf)                                                             \
  {                                                                                \
    _Pragma("unroll") for (int kvt = 0; kvt < 2; ++kvt)                            \
        _Pragma("unroll") for (int dc = 0; dc < 2; ++dc)                           \
            kf[kvt][dc] = *(const bf16x8*)&Kb[(size_t)((kv0) + kvt * 16 + fr) * 64 \
                                              + dc * 32 + g * 8];                  \
  }
  // V^T A-frag (16d x 32kv): lane(fr,g) -> V^T[dt*16+fr][kv0+g*8 ..+8]
#define LOADV(kv0, vf)                                                             \
  {                                                                                \
    _Pragma("unroll") for (int dt = 0; dt < 4; ++dt)                               \
        vf[dt] = *(const bf16x8*)&Vb[(size_t)(dt * 16 + fr) * Nn + (kv0) + g * 8]; \
  }

  // One 32-kv step: QK^T -> exp2 -> pack to P^T B-frags -> lse + PV
#define STEP(kf, vf)                                                               \
  {                                                                                \
    f32x4 st[2][4] = {};                                                           \
    __builtin_amdgcn_s_setprio(1);                                                 \
    _Pragma("unroll") for (int dc = 0; dc < 2; ++dc)                               \
        _Pragma("unroll") for (int kvt = 0; kvt < 2; ++kvt)                        \
            _Pragma("unroll") for (int qt = 0; qt < 4; ++qt)                       \
                st[kvt][qt] = __builtin_amdgcn_mfma_f32_16x16x32_bf16(             \
                    kf[kvt][dc], qf[qt][dc], st[kvt][qt], 0, 0, 0);                \
    __builtin_amdgcn_s_setprio(0);                                                 \
    _Pragma("unroll") for (int kvt = 0; kvt < 2; ++kvt)                            \
        _Pragma("unroll") for (int qt = 0; qt < 4; ++qt)                           \
            _Pragma("unroll") for (int r = 0; r < 4; ++r)                          \
                st[kvt][qt][r] = fast_exp2(st[kvt][qt][r]);                        \
    u32 pw[4][4];                                                                  \
    _Pragma("unroll") for (int qt = 0; qt < 4; ++qt) {                             \
      u32 a0 = cvtpk(st[0][qt][0], st[0][qt][1]);                                  \
      u32 a1 = cvtpk(st[0][qt][2], st[0][qt][3]);                                  \
      u32 b0 = cvtpk(st[1][qt][0], st[1][qt][1]);                                  \
      u32 b1 = cvtpk(st[1][qt][2], st[1][qt][3]);                                  \
      pl32swap(a0, b0); pl16swap(a0, b0);                                          \
      pl32swap(a1, b1); pl16swap(a1, b1);                                          \
      pw[qt][0] = a0; pw[qt][1] = a1; pw[qt][2] = b0; pw[qt][3] = b1;              \
    }                                                                              \
    __builtin_amdgcn_s_setprio(1);                                                 \
    _Pragma("unroll") for (int qt = 0; qt < 4; ++qt) {                             \
      union { u32 u[4]; bf16x8 v; } pu;                                            \
      pu.u[0] = pw[qt][0]; pu.u[1] = pw[qt][1];                                    \
      pu.u[2] = pw[qt][2]; pu.u[3] = pw[qt][3];                                    \
      f32x4 z = {0.f, 0.f, 0.f, 0.f};                                              \
      f32x4 rsv = __builtin_amdgcn_mfma_f32_16x16x32_bf16(onesv, pu.v, z, 0, 0, 0);\
      lse[qt] += rsv[0];                                                           \
      _Pragma("unroll") for (int dt = 0; dt < 4; ++dt)                             \
          ot[dt][qt] = __builtin_amdgcn_mfma_f32_16x16x32_bf16(                    \
              vf[dt], pu.v, ot[dt][qt], 0, 0, 0);                                  \
    }                                                                              \
    __builtin_amdgcn_s_setprio(0);                                                 \
  }

  bf16x8 kfA[2][2], vfA[4], kfB[2][2], vfB[4];
  LOADK(0, kfA); LOADV(0, vfA);
  // unroll-2 ping-pong: static register buffers (rule #20), prefetch 1 step ahead
  for (int it = 0; it < 64; it += 2) {
    LOADK((it + 1) * 32, kfB); LOADV((it + 1) * 32, vfB);
    STEP(kfA, vfA);
    if (it + 2 < 64) { LOADK((it + 2) * 32, kfA); LOADV((it + 2) * 32, vfA); }
    STEP(kfB, vfB);
  }

  // epilogue: normalize, write bf16 [B, N, H*64]
  const int b = bh >> 4, h = bh & 15;
#pragma unroll
  for (int qt = 0; qt < 4; ++qt) {
    const float inv = 1.f / lse[qt];
    const int tok = q0 + qt * 16 + fr;
    const size_t rowbase = ((size_t)b * Nn + tok) * Cc + h * 64;
#pragma unroll
    for (int dt = 0; dt < 4; ++dt) {
      ushort4 o4;
      o4.x = f2b(ot[dt][qt][0] * inv);
      o4.y = f2b(ot[dt][qt][1] * inv);
      o4.z = f2b(ot[dt][qt][2] * inv);
      o4.w = f2b(ot[dt][qt][3] * inv);
      *(ushort4*)&Og[rowbase + dt * 16 + g * 4] = o4;
    }
  }
#undef LOADK
#undef LOADV
#undef STEP
}

extern "C" void kernel_launch(void* const* d_in, const int* in_sizes, int n_in,
                              void* d_out, int out_size, void* d_ws, size_t ws_size,
                              hipStream_t stream) {
  const float* x      = (const float*)d_in[0];
  const float* w_qkv  = (const float*)d_in[1];
  const float* w_proj = (const float*)d_in[2];
  const float* b_proj = (const float*)d_in[3];
  float* out = (float*)d_out;

  // ws layout — 48 MB (proven safe):
  u16* xb     = (u16*)d_ws;                        // 4096*1024
  u16* wqkvb  = xb + (size_t)4096 * 1024;          // 3072*1024
  u16* wprojb = wqkvb + (size_t)3072 * 1024;       // 1024*1024
  u16* qkv    = wprojb + (size_t)1024 * 1024;      // 3*2*16*2048*64
  u16* ows    = qkv + (size_t)3 * Bb * Hh * Nn * Dd;  // 4096*1024
  u16* q  = qkv;
  u16* k  = qkv + (size_t)Bb * Hh * Nn * Dd;
  u16* vt = k + (size_t)Bb * Hh * Nn * Dd;         // [B][H][D][N]

  cvt_all<<<2048, 256, 0, stream>>>(x, xb, w_qkv, wqkvb, w_proj, wprojb);
  gemm_qkv<<<768, 256, 0, stream>>>(xb, wqkvb, qkv);
  attn_fwd<<<256, 256, 0, stream>>>(q, k, vt, ows);
  gemm_proj<<<256, 256, 0, stream>>>(ows, wprojb, out, b_proj);
}

// Round 12
// 107.576 us; speedup vs baseline: 1.4695x; 1.2564x over previous
//
#include <hip/hip_runtime.h>
#include <hip/hip_bf16.h>
#include <cstdint>

#define DEV __device__ __forceinline__

typedef float f32x4 __attribute__((ext_vector_type(4)));
typedef short bf16x8 __attribute__((ext_vector_type(8)));
typedef unsigned short u16;
typedef unsigned int u32;

constexpr int Bb = 2, Nn = 2048, Cc = 1024, Hh = 16, Dd = 64;
// 64^-0.5 * log2(e): folded into w_qkv's Q-rows at cvt; softmax runs in exp2 domain.
constexpr float QSCALE = 0.18033688011112042f;

// fp32 -> bf16 round-to-nearest-even
DEV u16 f2b(float f) {
  unsigned u = __float_as_uint(f);
  u += 0x7FFFu + ((u >> 16) & 1u);
  return (u16)(u >> 16);
}

DEV void gload_lds16(const u16* g, u16* l) {
  __builtin_amdgcn_global_load_lds(
      (const __attribute__((address_space(1))) void*)g,
      (__attribute__((address_space(3))) void*)l, 16, 0, 0);
}

// XOR swizzle for LDS tiles with 128B rows (64 bf16/row) — attn K/V tiles.
DEV int swz(int row, int byteInRow) {
  return row * 128 + (byteInRow ^ ((row & 7) << 4));
}
// 64B-row variant (GEMM BK=32 tiles)
DEV int swzp(int row, int byteInRow) {
  return row * 64 + (byteInRow ^ ((((row >> 2) + row) & 3) << 4));
}

DEV u32 cvtpk(float lo, float hi) {
  u32 r;
  asm("v_cvt_pk_bf16_f32 %0, %1, %2" : "=v"(r) : "v"(lo), "v"(hi));
  return r;
}
DEV void pl32swap(u32& a, u32& b) {
  asm("v_permlane32_swap_b32 %0, %1" : "+v"(a), "+v"(b));
}
DEV void pl16swap(u32& a, u32& b) {
  asm("v_permlane16_swap_b32 %0, %1" : "+v"(a), "+v"(b));
}

#if __has_builtin(__builtin_amdgcn_exp2f)
DEV float fast_exp2(float x) { return __builtin_amdgcn_exp2f(x); }
#else
DEV float fast_exp2(float x) { return exp2f(x); }
#endif

// ---------------- fused fp32 -> bf16 convert; scales w_qkv's Q-rows by QSCALE ----------------
__global__ void cvt_all(const float* __restrict__ x, u16* __restrict__ xb,
                        const float* __restrict__ wq, u16* __restrict__ wqb,
                        const float* __restrict__ wp, u16* __restrict__ wpb) {
  constexpr int n1 = 4096 * 1024 / 4, n2 = 3072 * 1024 / 4, n3 = 1024 * 1024 / 4;
  constexpr int nQ = 1024 * 1024 / 4;  // first 1024 rows of w_qkv = Q
  int idx = blockIdx.x * blockDim.x + threadIdx.x;
  int stride = gridDim.x * blockDim.x;
  for (int i = idx; i < n1 + n2 + n3; i += stride) {
    const float* in; u16* out; int j;
    float sc = 1.f;
    if (i < n1) { in = x; out = xb; j = i; }
    else if (i < n1 + n2) { in = wq; out = wqb; j = i - n1; if (j < nQ) sc = QSCALE; }
    else { in = wp; out = wpb; j = i - n1 - n2; }
    float4 v = ((const float4*)in)[j];
    ushort4 o;
    o.x = f2b(v.x * sc); o.y = f2b(v.y * sc); o.z = f2b(v.z * sc); o.w = f2b(v.w * sc);
    ((ushort4*)out)[j] = o;
  }
}

// ---------------- QKV GEMM: 128x128, BK=32, 3 blocks/CU, 1-barrier dbuf (round-7 exact) ----------------
__global__ __launch_bounds__(256) void gemm_qkv(
    const u16* __restrict__ A, const u16* __restrict__ W, u16* __restrict__ qkv_out) {
  constexpr int K = 1024, NT = K / 32;
  __shared__ __align__(16) u16 As[2][128 * 32];
  __shared__ __align__(16) u16 Bs[2][128 * 32];
  const int t = threadIdx.x, lane = t & 63;
  const int wm = t >> 7, wn = (t >> 6) & 1;
  const int bid = blockIdx.x;
  const int wg = (bid & 7) * 96 + (bid >> 3);
  const int bx = wg % 24, by = wg / 24;
  const int m0 = by * 128, n0 = bx * 128;
  const int fr = lane & 15, g = lane >> 4;

  const int srow = t >> 2;
  const int scp = (t & 3) ^ (((t >> 2) + (t >> 4)) & 3);
  const u16* gA = A + (size_t)(m0 + srow) * K + scp * 8;
  const u16* gW = W + (size_t)(n0 + srow) * K + scp * 8;

  f32x4 acc[4][4] = {};

#define STAGEQ(tile, buf)                                              \
  {                                                                    \
    const int k0_ = (tile) * 32;                                       \
    gload_lds16(gA + k0_, &As[buf][t * 8]);                            \
    gload_lds16(gA + k0_ + (size_t)64 * K, &As[buf][t * 8 + 2048]);    \
    gload_lds16(gW + k0_, &Bs[buf][t * 8]);                            \
    gload_lds16(gW + k0_ + (size_t)64 * K, &Bs[buf][t * 8 + 2048]);    \
  }

  STAGEQ(0, 0);
  __syncthreads();

  for (int tt = 0; tt < NT; ++tt) {
    const int cur = tt & 1;
    if (tt + 1 < NT) STAGEQ(tt + 1, cur ^ 1);
    const char* Ac = (const char*)As[cur];
    const char* Bc = (const char*)Bs[cur];
    bf16x8 af[4], bfr[4];
#pragma unroll
    for (int i = 0; i < 4; ++i)
      af[i] = *(const bf16x8*)(Ac + swzp(wm * 64 + i * 16 + fr, g * 16));
#pragma unroll
    for (int j = 0; j < 4; ++j)
      bfr[j] = *(const bf16x8*)(Bc + swzp(wn * 64 + j * 16 + fr, g * 16));
    __builtin_amdgcn_s_setprio(1);
#pragma unroll
    for (int i = 0; i < 4; ++i)
#pragma unroll
      for (int j = 0; j < 4; ++j)
        acc[i][j] = __builtin_amdgcn_mfma_f32_16x16x32_bf16(af[i], bfr[j], acc[i][j], 0, 0, 0);
    __builtin_amdgcn_s_setprio(0);
    __syncthreads();
  }

  const int rg = g * 4;
#pragma unroll
  for (int mi = 0; mi < 4; ++mi) {
#pragma unroll
    for (int ni = 0; ni < 4; ++ni) {
      const int col = n0 + wn * 64 + ni * 16 + fr;
      const int s = col >> 10, h = (col >> 6) & 15, d = col & 63;
      const int row0 = m0 + wm * 64 + mi * 16 + rg;
      const int b = row0 >> 11, nb = row0 & 2047;
      if (s == 2) {
        ushort4 o4;
        o4.x = f2b(acc[mi][ni][0]); o4.y = f2b(acc[mi][ni][1]);
        o4.z = f2b(acc[mi][ni][2]); o4.w = f2b(acc[mi][ni][3]);
        const size_t off = (size_t)2 * Bb * Hh * Nn * Dd +
                           (((size_t)b * Hh + h) * Dd + d) * Nn + nb;
        *(ushort4*)&qkv_out[off] = o4;
      } else {
#pragma unroll
        for (int r = 0; r < 4; ++r) {
          const size_t off = ((((size_t)s * Bb + b) * Hh + h) * Nn + (nb + r)) * Dd + d;
          qkv_out[off] = f2b(acc[mi][ni][r]);
        }
      }
    }
  }
#undef STAGEQ
}

// ---------------- proj GEMM: 64x128 tile, 512 blocks (2/CU, 8 waves/CU), dbuf ----------------
__global__ __launch_bounds__(256, 2) void gemm_proj(
    const u16* __restrict__ A, const u16* __restrict__ W,
    float* __restrict__ fout, const float* __restrict__ bias) {
  constexpr int K = 1024, Nmat = 1024, NT = K / 32;
  __shared__ __align__(16) u16 As[2][64 * 32];
  __shared__ __align__(16) u16 Bs[2][128 * 32];
  const int t = threadIdx.x, lane = t & 63, w = t >> 6;  // 4 waves, n-slices of 32
  const int bid = blockIdx.x;
  const int wg = (bid & 7) * 64 + (bid >> 3);            // 512 % 8 == 0, bijective
  const int bx = wg & 7, by = wg >> 3;
  const int m0 = by * 64, n0 = bx * 128;
  const int fr = lane & 15, g = lane >> 4;

  const int srow = t >> 2;
  const int scp = (t & 3) ^ (((t >> 2) + (t >> 4)) & 3);
  const u16* gA = A + (size_t)(m0 + srow) * K + scp * 8;
  const u16* gW = W + (size_t)(n0 + srow) * K + scp * 8;

  f32x4 acc[4][2] = {};

#define STAGEP(tile, buf)                                              \
  {                                                                    \
    const int k0_ = (tile) * 32;                                       \
    gload_lds16(gA + k0_, &As[buf][t * 8]);                            \
    gload_lds16(gW + k0_, &Bs[buf][t * 8]);                            \
    gload_lds16(gW + k0_ + (size_t)64 * K, &Bs[buf][t * 8 + 2048]);    \
  }

  STAGEP(0, 0);
  __syncthreads();

  for (int tt = 0; tt < NT; ++tt) {
    const int cur = tt & 1;
    if (tt + 1 < NT) STAGEP(tt + 1, cur ^ 1);
    const char* Ac = (const char*)As[cur];
    const char* Bc = (const char*)Bs[cur];
    bf16x8 af[4], bfr[2];
#pragma unroll
    for (int i = 0; i < 4; ++i)
      af[i] = *(const bf16x8*)(Ac + swzp(i * 16 + fr, g * 16));
#pragma unroll
    for (int j = 0; j < 2; ++j)
      bfr[j] = *(const bf16x8*)(Bc + swzp(w * 32 + j * 16 + fr, g * 16));
    __builtin_amdgcn_s_setprio(1);
#pragma unroll
    for (int i = 0; i < 4; ++i)
#pragma unroll
      for (int j = 0; j < 2; ++j)
        acc[i][j] = __builtin_amdgcn_mfma_f32_16x16x32_bf16(af[i], bfr[j], acc[i][j], 0, 0, 0);
    __builtin_amdgcn_s_setprio(0);
    __syncthreads();
  }

  const int rg = g * 4;
#pragma unroll
  for (int i = 0; i < 4; ++i)
#pragma unroll
    for (int j = 0; j < 2; ++j) {
      const int col = n0 + w * 32 + j * 16 + fr;
#pragma unroll
      for (int r = 0; r < 4; ++r) {
        const int row = m0 + i * 16 + rg + r;
        fout[(size_t)row * Nmat + col] = acc[i][j][r] + bias[col];
      }
    }
#undef STAGEP
}

// ---------------- flash attention v4 (round-7 exact): 8 waves, 4 waves/SIMD TLP ----------------
// 1 block = 128 q-rows of one (b,h), 512 threads. Wave w: q-group qg=w>>1
// (32 rows, in-register B-frags), kv-half kh=w&1 (32 kv). 16 waves/CU.
// P = exp2(S^T) direct (no max tracking; logits bounded ~2^20), lse via
// ones-MFMA; kv-half partials combined through LDS at the end.
__global__ __launch_bounds__(512, 4) void attn_fwd(
    const u16* __restrict__ Qg, const u16* __restrict__ Kg,
    const u16* __restrict__ Vtg, u16* __restrict__ Og) {
  __shared__ __align__(16) char smem[34816];  // [0,32768): K/V dbuf; epilogue aliases
  const int t = threadIdx.x, lane = t & 63, w = t >> 6;
  const int qg = w >> 1, kh = w & 1;
  // XCD-chunked swizzle: the 16 q-blocks of one head land on one XCD's L2.
  const int wg = ((blockIdx.x & 7) << 6) | (blockIdx.x >> 3);
  const int bh = wg >> 4;
  const int q0 = (wg & 15) * 128;
  const size_t base = (size_t)bh * Nn * Dd;
  const u16* Qb = Qg + base;
  const u16* Kb = Kg + base;
  const u16* Vb = Vtg + base;  // [D=64][N=2048]
  const int fr = lane & 15, g = lane >> 4;

  bf16x8 onesv;
  {
    union { u32 u[4]; bf16x8 v; } o_;
#pragma unroll
    for (int i = 0; i < 4; ++i) o_.u[i] = 0x3F803F80u;
    onesv = o_.v;
  }

  // Q as MFMA-B fragments: 32 q-rows per wave
  bf16x8 qf[2][2];
#pragma unroll
  for (int qt = 0; qt < 2; ++qt)
#pragma unroll
    for (int dc = 0; dc < 2; ++dc)
      qf[qt][dc] = *(const bf16x8*)&Qb[(size_t)(q0 + qg * 32 + qt * 16 + fr) * 64 + dc * 32 + g * 8];

  f32x4 ot[4][2] = {};            // [dt][qt]: O^T partial, rows d, cols q
  float lse[2] = {0.f, 0.f};

  // block-cooperative staging: 512 threads, 1 uint4 of K + 1 of V each
  const int srow = t >> 3, scb = t & 7;   // srow in [0,64)
  const u16* kp = Kb + srow * 64 + scb * 8;
  const u16* vp = Vb + (size_t)srow * Nn + scb * 8;
  uint4 kreg, vreg;

#define LOADT(tile)                                        \
  {                                                        \
    kreg = *(const uint4*)(kp + (size_t)(tile) * 4096);    \
    vreg = *(const uint4*)(vp + (size_t)(tile) * 64);      \
  }
#define STORET(buf)                                        \
  {                                                        \
    char* kb_ = smem + (buf) * 16384;                      \
    *(uint4*)(kb_ + swz(srow, scb * 16)) = kreg;           \
    *(uint4*)(kb_ + 8192 + swz(srow, scb * 16)) = vreg;    \
  }

  LOADT(0);
  STORET(0);
  __syncthreads();

  for (int it = 0; it < 32; ++it) {
    const int cur = it & 1;
    const char* Kst = smem + cur * 16384;
    const char* Vst = Kst + 8192;
    if (it < 31) LOADT(it + 1);  // issue-early; lands under compute (T14)

    // ---- S^T = K_half · Q^T : rows kv (kh*32 + kvt*16 + 4g + r), cols q ----
    bf16x8 kf[2][2];
#pragma unroll
    for (int kvt = 0; kvt < 2; ++kvt)
#pragma unroll
      for (int dc = 0; dc < 2; ++dc)
        kf[kvt][dc] = *(const bf16x8*)(Kst + swz(kh * 32 + kvt * 16 + fr, dc * 64 + g * 16));
    f32x4 st[2][2] = {};
    __builtin_amdgcn_s_setprio(1);
#pragma unroll
    for (int dc = 0; dc < 2; ++dc)
#pragma unroll
      for (int kvt = 0; kvt < 2; ++kvt)
#pragma unroll
        for (int qt = 0; qt < 2; ++qt)
          st[kvt][qt] = __builtin_amdgcn_mfma_f32_16x16x32_bf16(kf[kvt][dc], qf[qt][dc], st[kvt][qt], 0, 0, 0);
    __builtin_amdgcn_s_setprio(0);

    // ---- P = exp2(S^T); assemble P^T B-frags in registers ----
#pragma unroll
    for (int kvt = 0; kvt < 2; ++kvt)
#pragma unroll
      for (int qt = 0; qt < 2; ++qt)
#pragma unroll
        for (int r = 0; r < 4; ++r)
          st[kvt][qt][r] = fast_exp2(st[kvt][qt][r]);

    u32 pw[2][4];
#pragma unroll
    for (int qt = 0; qt < 2; ++qt) {
      u32 a0 = cvtpk(st[0][qt][0], st[0][qt][1]);
      u32 a1 = cvtpk(st[0][qt][2], st[0][qt][3]);
      u32 b0 = cvtpk(st[1][qt][0], st[1][qt][1]);
      u32 b1 = cvtpk(st[1][qt][2], st[1][qt][3]);
      pl32swap(a0, b0); pl16swap(a0, b0);
      pl32swap(a1, b1); pl16swap(a1, b1);
      pw[qt][0] = a0; pw[qt][1] = a1; pw[qt][2] = b0; pw[qt][3] = b1;
    }

    // ---- lse via ones-MFMA; O^T += V_half^T · P^T ----
    bf16x8 vf[4];
#pragma unroll
    for (int dt = 0; dt < 4; ++dt)
      vf[dt] = *(const bf16x8*)(Vst + swz(dt * 16 + fr, kh * 64 + g * 16));
    __builtin_amdgcn_s_setprio(1);
#pragma unroll
    for (int qt = 0; qt < 2; ++qt) {
      union { u32 u[4]; bf16x8 v; } pu;
      pu.u[0] = pw[qt][0]; pu.u[1] = pw[qt][1]; pu.u[2] = pw[qt][2]; pu.u[3] = pw[qt][3];
      f32x4 z = {0.f, 0.f, 0.f, 0.f};
      f32x4 rsv = __builtin_amdgcn_mfma_f32_16x16x32_bf16(onesv, pu.v, z, 0, 0, 0);
      lse[qt] += rsv[0];
#pragma unroll
      for (int dt = 0; dt < 4; ++dt)
        ot[dt][qt] = __builtin_amdgcn_mfma_f32_16x16x32_bf16(vf[dt], pu.v, ot[dt][qt], 0, 0, 0);
    }
    __builtin_amdgcn_s_setprio(0);

    if (it < 31) {
      STORET(cur ^ 1);   // writes buf cur^1; all reads this iter hit buf cur
      __syncthreads();   // single barrier per iter
    }
  }

  // ---- combine kv-halves through LDS (aliases dead K/V buffers) ----
  __syncthreads();
  float* Ob = (float*)(smem + qg * 8448);             // [32 q][stride 66] f32
  float* Lb = (float*)(smem + 33792 + qg * 128);      // [32 q] f32
  if (kh) {
#pragma unroll
    for (int qt = 0; qt < 2; ++qt) {
#pragma unroll
      for (int dt = 0; dt < 4; ++dt)
#pragma unroll
        for (int r = 0; r < 4; ++r)
          Ob[(qt * 16 + fr) * 66 + dt * 16 + 4 * g + r] = ot[dt][qt][r];
      if (g == 0) Lb[qt * 16 + fr] = lse[qt];
    }
  }
  __syncthreads();
  if (!kh) {
    const int b = bh >> 4, h = bh & 15;
#pragma unroll
    for (int qt = 0; qt < 2; ++qt) {
      const float inv = 1.f / (lse[qt] + Lb[qt * 16 + fr]);
      const int tok = q0 + qg * 32 + qt * 16 + fr;
      const size_t rowbase = ((size_t)b * Nn + tok) * Cc + h * 64;
#pragma unroll
      for (int dt = 0; dt < 4; ++dt) {
        ushort4 o4;
        o4.x = f2b((ot[dt][qt][0] + Ob[(qt * 16 + fr) * 66 + dt * 16 + 4 * g + 0]) * inv);
        o4.y = f2b((ot[dt][qt][1] + Ob[(qt * 16 + fr) * 66 + dt * 16 + 4 * g + 1]) * inv);
        o4.z = f2b((ot[dt][qt][2] + Ob[(qt * 16 + fr) * 66 + dt * 16 + 4 * g + 2]) * inv);
        o4.w = f2b((ot[dt][qt][3] + Ob[(qt * 16 + fr) * 66 + dt * 16 + 4 * g + 3]) * inv);
        *(ushort4*)&Og[rowbase + dt * 16 + g * 4] = o4;
      }
    }
  }
#undef LOADT
#undef STORET
}

extern "C" void kernel_launch(void* const* d_in, const int* in_sizes, int n_in,
                              void* d_out, int out_size, void* d_ws, size_t ws_size,
                              hipStream_t stream) {
  const float* x      = (const float*)d_in[0];
  const float* w_qkv  = (const float*)d_in[1];
  const float* w_proj = (const float*)d_in[2];
  const float* b_proj = (const float*)d_in[3];
  float* out = (float*)d_out;

  // ws layout — 48 MB (proven safe):
  u16* xb     = (u16*)d_ws;                        // 4096*1024
  u16* wqkvb  = xb + (size_t)4096 * 1024;          // 3072*1024
  u16* wprojb = wqkvb + (size_t)3072 * 1024;       // 1024*1024
  u16* qkv    = wprojb + (size_t)1024 * 1024;      // 3*2*16*2048*64
  u16* ows    = qkv + (size_t)3 * Bb * Hh * Nn * Dd;  // 4096*1024
  u16* q  = qkv;
  u16* k  = qkv + (size_t)Bb * Hh * Nn * Dd;
  u16* vt = k + (size_t)Bb * Hh * Nn * Dd;         // [B][H][D][N]

  cvt_all<<<2048, 256, 0, stream>>>(x, xb, w_qkv, wqkvb, w_proj, wprojb);
  gemm_qkv<<<768, 256, 0, stream>>>(xb, wqkvb, qkv);
  attn_fwd<<<512, 512, 0, stream>>>(q, k, vt, ows);
  gemm_proj<<<512, 256, 0, stream>>>(ows, wprojb, out, b_proj);
}